// Round 1
// baseline (360.576 us; speedup 1.0000x reference)
//
#include <hip/hip_runtime.h>
#include <stdint.h>

#define LDIFF 0.24f

constexpr int H = 512, W = 512, NB = 2;
constexpr int HW = H * W;              // 2^18
constexpr int N_D = NB * HW;           // 524288
constexpr int CVH = 511, CVW = 512;
constexpr int CHH = 512, CHW = 511;
constexpr int N_CV = NB * CVH * CVW;   // 523264
constexpr int NBLKS = 11;              // 11x11 blocks, step 48
constexpr int NBT = NB * 121;          // 242 workgroups <= 256 CUs -> co-resident

// LLC-coherent (cross-XCD) access: relaxed agent atomics = sc1 ops through the
// Infinity Cache. Validated in prior session R4-R9.
__device__ inline float ldc(const float* p) {
    return __hip_atomic_load(p, __ATOMIC_RELAXED, __HIP_MEMORY_SCOPE_AGENT);
}
__device__ inline void stc(float* p, float v) {
    __hip_atomic_store(p, v, __ATOMIC_RELAXED, __HIP_MEMORY_SCOPE_AGENT);
}
__device__ inline int ldci(const int* p) {
    return __hip_atomic_load(p, __ATOMIC_RELAXED, __HIP_MEMORY_SCOPE_AGENT);
}
__device__ inline void stci(int* p, int v) {
    __hip_atomic_store(p, v, __ATOMIC_RELAXED, __HIP_MEMORY_SCOPE_AGENT);
}

// wave64 DPP rotate/shift by 1 (VALU pipe, zero LDS traffic). Direction probed
// at runtime (dirL); the wavefront stencil's use (lf+rt) is direction-agnostic.
__device__ inline float rot_a(float x) {
    return __int_as_float(__builtin_amdgcn_update_dpp(0, __float_as_int(x), 0x134, 0xf, 0xf, false));
}
__device__ inline float rot_b(float x) {
    return __int_as_float(__builtin_amdgcn_update_dpp(0, __float_as_int(x), 0x13c, 0xf, 0xf, false));
}
__device__ inline float sh_a(float x) {
    return __int_as_float(__builtin_amdgcn_update_dpp(0, __float_as_int(x), 0x130, 0xf, 0xf, true));
}
__device__ inline float sh_b(float x) {
    return __int_as_float(__builtin_amdgcn_update_dpp(0, __float_as_int(x), 0x138, 0xf, 0xf, true));
}

// ======================= ONE kernel, zero global barriers =======================
//  A) local cv/ch halo tile (73x73) into LDS; write disjoint cv/ch partition;
//     params via wave butterfly.
//  B) wavefront with DATA-AS-FLAG handoff: each block writes only its exclusive
//     48x48 final core into D (cores tile the plane -> no WW/WAR hazards) and
//     publishes right (64x16) / bottom (16x64) strips into dedicated per-block
//     edge buffers, NaN-sentinel (0xFFFFFFFF) initialized. Consumers poll their
//     own needed words: one load = detect + data. No producer vmcnt drain, no
//     flag round trip, no post-flag data load.
//  C) diffusion 8 stages x 8 iters; stage-1 wait is merged into the load via
//     the same sentinel poll on D; stages 2..8 keep dflag chaining.
__global__ __launch_bounds__(256, 1) void kall(
    const float* __restrict__ guide, const float* __restrict__ initial,
    float* __restrict__ cv, float* __restrict__ ch,
    float* __restrict__ D, float* __restrict__ EDG,
    float* __restrict__ T0, float* __restrict__ T1,
    float* __restrict__ ypred, int* __restrict__ dflag)
{
    __shared__ float cvT[73 * 74];
    __shared__ float chT[73 * 74];
    __shared__ float xT[2][4][64];
    __shared__ float xB[2][4][64];
    __shared__ float red[12];
    __shared__ float prmS[3];

    const int blk = blockIdx.x;           // 0..120
    const int i = blk / NBLKS, j = blk % NBLKS;
    const int b = blockIdx.y;
    const int tid = threadIdx.x;
    const int lane = tid & 63, wv = tid >> 6;
    const int r0 = wv * 16;
    const int me = b * 121 + blk;

    const int y0 = i * 48, x0 = j * 48;
    const int y1 = min(y0 + 64, 512), x1 = min(x0 + 64, 512);
    const int bh = y1 - y0, bw = x1 - x0;
    const int yb = y0 - 8, xb = x0 - 8;
    const float kinv = 1.0f / (0.03f * 0.03f);

    // ===== A1: local cv/ch (rows yb..yb+72, cols xb..xb+72; 0 outside valid) =====
    const float* gb = guide + (size_t)b * 3 * HW;
    for (int p = tid; p < 73 * 73; p += 256) {
        int rr = p / 73, cc2 = p - rr * 73;
        int y = yb + rr, x = xb + cc2;
        float cvv = 0.0f, chv = 0.0f;
        if (y >= 0 && y < 512 && x >= 0 && x < 512) {
            const float* g = gb + y * W + x;
            float g0 = g[0], g1 = g[HW], g2 = g[2 * HW];
            if (y < 511) {
                float d = (fabsf(g[W] - g0) + fabsf(g[HW + W] - g1) + fabsf(g[2 * HW + W] - g2)) * (1.0f / 3.0f);
                cvv = 1.0f / (1.0f + d * d * kinv);
            }
            if (x < 511) {
                float d = (fabsf(g[1] - g0) + fabsf(g[HW + 1] - g1) + fabsf(g[2 * HW + 1] - g2)) * (1.0f / 3.0f);
                chv = 1.0f / (1.0f + d * d * kinv);
            }
        }
        cvT[rr * 74 + cc2] = cvv;
        chT[rr * 74 + cc2] = chv;
    }
    __syncthreads();

    // ===== A2: write disjoint cv/ch output partitions (48x48 cores) =====
    {
        int rcv = min(y0 + 48, CVH) - y0, ccv = min(x0 + 48, CVW) - x0;
        float* cvo = cv + b * CVH * CVW;
        for (int p = tid; p < rcv * ccv; p += 256) {
            int r = p / ccv, c = p - r * ccv;
            cvo[(y0 + r) * CVW + x0 + c] = cvT[(r + 8) * 74 + c + 8];
        }
        int rch = min(y0 + 48, CHH) - y0, cch = min(x0 + 48, CHW) - x0;
        float* cho = ch + b * CHH * CHW;
        for (int p = tid; p < rch * cch; p += 256) {
            int r = p / cch, c = p - r * cch;
            cho[(y0 + r) * CHW + x0 + c] = chT[(r + 8) * 74 + c + 8];
        }
    }

    // ===== A3: params — wave butterfly + 1 barrier =====
    float scv = 0.f, sch = 0.f, sun = 0.f;
    {
        int n = (bh - 1) * bw;
        for (int p = tid; p < n; p += 256) { int r = p / bw, c = p - r * bw; scv += cvT[(r + 8) * 74 + c + 8]; }
    }
    {
        int cols = bw - 1, n = bh * cols;
        for (int p = tid; p < n; p += 256) { int r = p / cols, c = p - r * cols; sch += chT[(r + 8) * 74 + c + 8]; }
    }
    const int ur = min(y1, 511) - y0, uc = min(x1, 511) - x0;
    {
        int n = ur * uc;
        for (int p = tid; p < n; p += 256) {
            int r = p / uc, c = p - r * uc;
            float s1 = 0.f, s2 = 0.f, t1 = 0.f, t2 = 0.f;
            #pragma unroll
            for (int dy = 0; dy < 3; dy++)
                #pragma unroll
                for (int dx = 0; dx < 3; dx++) {
                    float v = cvT[(r + 7 + dy) * 74 + c + 7 + dx]; s1 += v; s2 += v * v;
                    float w2 = chT[(r + 7 + dy) * 74 + c + 7 + dx]; t1 += w2; t2 += w2 * w2;
                }
            float m = s1 * (1.0f / 9.0f);
            float vcv = s2 * (1.0f / 9.0f) - m * m;
            m = t1 * (1.0f / 9.0f);
            float vch = t2 * (1.0f / 9.0f) - m * m;
            if (vcv < 0.1f && vch < 0.1f) sun += 1.f;
        }
    }
    #pragma unroll
    for (int m = 1; m < 64; m <<= 1) {
        scv += __shfl_xor(scv, m);
        sch += __shfl_xor(sch, m);
        sun += __shfl_xor(sun, m);
    }
    if (lane == 0) { red[wv * 3] = scv; red[wv * 3 + 1] = sch; red[wv * 3 + 2] = sun; }
    __syncthreads();
    if (tid == 0) {
        float a0 = red[0] + red[3] + red[6] + red[9];
        float a1 = red[1] + red[4] + red[7] + red[10];
        float a2 = red[2] + red[5] + red[8] + red[11];
        prmS[0] = a0 / (float)((bh - 1) * bw);
        prmS[1] = a1 / (float)(bh * (bw - 1));
        prmS[2] = (a2 / (float)(ur * uc) > 0.7f) ? 1.0f : 0.0f;
    }
    __syncthreads();

    // DPP direction probe (wave-uniform)
    int prb = __builtin_amdgcn_update_dpp(0, lane, 0x134, 0xf, 0xf, false);
    const bool dirL = (prb == ((lane + 63) & 63));

    const bool cond = prmS[2] > 0.5f;
    const float a = LDIFF * prmS[0], bc = LDIFF * prmS[1];
    float* Db = D + b * HW;
    const float* ini = initial + b * HW;
    float* RG = EDG + (size_t)me * 2048;        // my right strip  [64][16]
    float* BG = RG + 1024;                      // my bottom strip [16][64]

    // ===== B: wavefront, data-as-flag =====
    const int mh = bh - 1, mw = bw - 1;
    const int ccw = lane & mw;

    float u[16], orig[16];
    {
        // Per-cell source of the "orig" value (= last writer before me in
        // reference row-major order):
        //   c<16, j>0            -> L's right strip  (all rows)
        //   r<16, i>0, c>=48     -> UR's bottom strip (cols 0..15 of UR)
        //   r<16, i>0, c<48      -> U's bottom strip
        //   else                 -> initial
        const int* sp[16];
        uint32_t pend = 0;
        #pragma unroll
        for (int k = 0; k < 16; k++) {
            int rr = (r0 + k) & mh;
            const float* p = nullptr;
            if (j > 0 && ccw < 16)
                p = EDG + (size_t)(me - 1) * 2048 + rr * 16 + ccw;                      // R[L]
            else if (i > 0 && rr < 16)
                p = (ccw >= 48) ? (EDG + (size_t)(me - NBLKS + 1) * 2048 + 1024 + rr * 64 + (ccw - 48))   // Bo[UR]
                                : (EDG + (size_t)(me - NBLKS) * 2048 + 1024 + rr * 64 + ccw);             // Bo[U]
            sp[k] = (const int*)p;
            if (p) pend |= 1u << k;
            else   orig[k] = ini[(y0 + rr) * W + x0 + ccw];
        }
        // two-pass poll: issue all masked loads, then test -> loads pipeline
        while (pend) {
            int vv[16];
            #pragma unroll
            for (int k = 0; k < 16; k++) if (pend & (1u << k)) vv[k] = ldci(sp[k]);
            uint32_t np = 0;
            #pragma unroll
            for (int k = 0; k < 16; k++) if (pend & (1u << k)) {
                if (vv[k] != -1) orig[k] = __int_as_float(vv[k]); else np |= 1u << k;
            }
            pend = np;
            if (pend) __builtin_amdgcn_s_sleep(2);   // throttle LLC poll pressure
        }
    }
    #pragma unroll
    for (int k = 0; k < 16; k++) u[k] = orig[k];

    if (cond) {
        int bs = 0;
        for (int it = 0; it < 10; it++) {
            xT[bs][wv][lane] = u[0];
            xB[bs][wv][lane] = u[15];
            __syncthreads();
            float ub = xB[bs][(wv + 3) & 3][lane];   // row r0-1 (periodic)
            float ut = xT[bs][(wv + 1) & 3][lane];   // row r0+16 (periodic)
            float nu[16];
            #pragma unroll
            for (int k = 0; k < 16; k++) {
                float up = (k == 0) ? ub : u[k - 1];
                float dn = (k == 15) ? ut : u[k + 1];
                float hsum = rot_a(u[k]) + rot_b(u[k]);
                nu[k] = u[k] + a * (up + dn - 2.0f * u[k]) + bc * (hsum - 2.0f * u[k]);
            }
            #pragma unroll
            for (int k = 0; k < 16; k++) u[k] = nu[k];
            bs ^= 1;
        }
    }

    // blend into final values; publish edge strips FIRST (consumers wait on them)
    #pragma unroll
    for (int k = 0; k < 16; k++) {
        int r = r0 + k;
        if (r < bh && lane < bw) {
            if (cond) {
                float byw = (y0 > 0 && r < 16) ? (float)r * (1.0f / 16.0f) : 1.0f;
                float bxw = (x0 > 0 && lane < 16) ? (float)lane * (1.0f / 16.0f) : 1.0f;
                float wgt = byw * bxw;
                u[k] = orig[k] * (1.0f - wgt) + u[k] * wgt;
            }
            if (bw == 64 && lane >= 48) stc(RG + r * 16 + (lane - 48), u[k]);   // right strip (j<10)
            if (r >= 48)                stc(BG + (r - 48) * 64 + lane, u[k]);   // bottom strip (i<10)
        }
    }
    // exclusive final 48x48 core -> D (cores tile the plane; no WW hazard)
    #pragma unroll
    for (int k = 0; k < 16; k++) {
        int r = r0 + k;
        if (r < 48 && r < bh && lane < 48 && lane < bw)
            stc(&Db[(y0 + r) * W + x0 + lane], u[k]);
    }
    __syncthreads();

    // ===== C: diffusion, 8 stages x 8 iters =====
    const int cx = xb + lane;
    const int gxc = min(max(cx, 0), 511);
    float cvr[16], chr[16], chl[16];
    int gyA[16];
    #pragma unroll
    for (int k = 0; k < 16; k++) {
        int cy = yb + r0 + k;
        gyA[k] = min(max(cy, 0), 511);
        cvr[k] = cvT[(r0 + k) * 74 + lane];    // 0 outside valid by construction
        chr[k] = chT[(r0 + k) * 74 + lane];
        chl[k] = dirL ? sh_a(chr[k]) : sh_b(chr[k]);   // lane0 -> 0 (halo col)
    }
    const float cvm1 = (wv == 0) ? 0.0f : cvT[(r0 - 1) * 74 + lane];

    float* Tb0 = T0 + b * HW;
    float* Tb1 = T1 + b * HW;
    float* ypb = ypred + b * HW;
    const bool cok = (lane >= 8 && lane < 56 && xb + lane < 512);

    for (int t = 1; t <= 8; t++) {
        const float* src = (t == 1) ? Db : (((t - 1) & 1) ? Tb1 : Tb0);
        float uc2[16];
        if (t == 1) {
            // wait merged into load: poll own 16 words of D until non-sentinel
            uint32_t pend = 0xFFFFu;
            while (pend) {
                int vv[16];
                #pragma unroll
                for (int k = 0; k < 16; k++) if (pend & (1u << k))
                    vv[k] = ldci((const int*)(src + gyA[k] * W + gxc));
                uint32_t np = 0;
                #pragma unroll
                for (int k = 0; k < 16; k++) if (pend & (1u << k)) {
                    if (vv[k] != -1) uc2[k] = __int_as_float(vv[k]); else np |= 1u << k;
                }
                pend = np;
                if (pend) __builtin_amdgcn_s_sleep(2);
            }
        } else {
            if (wv == 0) {
                bool need = false;
                const int* fp = dflag;
                const int thr = t - 1;
                if (lane < 9) {
                    int di = lane / 3 - 1, dj = lane % 3 - 1;
                    int ni = i + di, nj = j + dj;
                    if ((di | dj) != 0 && ni >= 0 && ni < NBLKS && nj >= 0 && nj < NBLKS) {
                        need = true;
                        fp = &dflag[(b * 121 + ni * NBLKS + nj) * 16];
                    }
                }
                while (true) {
                    int v = need ? ldci(fp) : 0x7fffffff;
                    if (__ballot(v < thr) == 0) break;
                    __builtin_amdgcn_s_sleep(4);
                }
            }
            __syncthreads();
            #pragma unroll
            for (int k = 0; k < 16; k++) uc2[k] = ldc(src + gyA[k] * W + gxc);
        }

        int bs = 0;
        for (int it = 0; it < 8; it++) {
            xT[bs][wv][lane] = uc2[0];
            xB[bs][wv][lane] = uc2[15];
            __syncthreads();
            float ub = (wv > 0) ? xB[bs][wv - 1][lane] : uc2[0];
            float ut = (wv < 3) ? xT[bs][wv + 1][lane] : uc2[15];
            float V[16];
            #pragma unroll
            for (int k = 0; k < 16; k++) {
                float up = (k == 0) ? ub : uc2[k - 1];
                float dn = (k == 15) ? ut : uc2[k + 1];
                float cup = (k == 0) ? cvm1 : cvr[k - 1];
                V[k] = uc2[k] + LDIFF * cvr[k] * (dn - uc2[k]) - LDIFF * cup * (uc2[k] - up);
            }
            #pragma unroll
            for (int k = 0; k < 16; k++) {
                float rA = rot_a(V[k]);
                float rB = rot_b(V[k]);
                float lf = dirL ? rA : rB;
                float rt = dirL ? rB : rA;
                uc2[k] = V[k] + LDIFF * chr[k] * (rt - V[k]) - LDIFF * chl[k] * (V[k] - lf);
            }
            bs ^= 1;
        }

        if (t < 8) {
            float* dst = (t & 1) ? Tb1 : Tb0;
            if (cok) {
                #pragma unroll
                for (int k = 0; k < 16; k++) {
                    int r = r0 + k;
                    if (r >= 8 && r < 56) {
                        int y = yb + r;
                        if (y < 512) stc(&dst[y * W + xb + lane], uc2[k]);
                    }
                }
            }
            asm volatile("s_waitcnt vmcnt(0)" ::: "memory");
            __syncthreads();
            if (tid == 0) stci(&dflag[me * 16], t);
        } else {
            if (cok) {
                #pragma unroll
                for (int k = 0; k < 16; k++) {
                    int r = r0 + k;
                    if (r >= 8 && r < 56) {
                        int y = yb + r;
                        if (y < 512) ypb[y * W + xb + lane] = uc2[k];
                    }
                }
            }
        }
    }
}

extern "C" void kernel_launch(void* const* d_in, const int* in_sizes, int n_in,
                              void* d_out, int out_size, void* d_ws, size_t ws_size,
                              hipStream_t stream) {
    const float* guide   = (const float*)d_in[0];
    const float* initial = (const float*)d_in[1];
    float* y_pred = (float*)d_out;
    float* cv = y_pred + N_D;          // output 1
    float* ch = cv + N_CV;             // output 2

    uint8_t* w = (uint8_t*)d_ws;
    int* dflag = (int*)w;                                          // 242*16 ints, zero-init
    float* D   = (float*)(w + 65536);                              // 2 MB, sentinel-init
    float* EDG = (float*)(w + 65536 + (size_t)N_D * 4);            // 242*8 KB, sentinel-init
    float* T0  = (float*)(w + 65536 + (size_t)N_D * 4 + (size_t)NBT * 8192);
    float* T1  = T0 + N_D;
    // total ws use: 64 KB + 2 MB + ~1.9 MB + 2*2 MB ~= 8.3 MB

    (void)hipMemsetAsync(w, 0, 65536, stream);
    (void)hipMemsetAsync(w + 65536, 0xFF, (size_t)N_D * 4 + (size_t)NBT * 8192, stream);
    kall<<<dim3(121, NB), 256, 0, stream>>>(guide, initial, cv, ch, D, EDG, T0, T1, y_pred, dflag);
}